// Round 14
// baseline (2418.932 us; speedup 1.0000x reference)
//
#include <hip/hip_runtime.h>
#include <hip/hip_bf16.h>
#include <stdint.h>

// ---------------------------------------------------------------------------
// MoDEChameleonMLP, round 14: r13 + K-loop `#pragma unroll 2` (NT even for
// both GEMMs) -> `cur` becomes compile-time constant per sub-body; double-
// buffer bases fold to static offsets (removes per-tile select + ~30 VALU
// address ops; longer straight-line region for the scheduler).
// Everything else r13-exact (verified 1420.7us).
// ---------------------------------------------------------------------------

#define H_DIM 4096
#define I_DIM 11008
#define N_TOK 4096
#define R_RANK 8
#define K1P 4224
#define K2P 11136

typedef __attribute__((ext_vector_type(8))) __bf16 bf16x8;
typedef __attribute__((ext_vector_type(4))) __bf16 bf16x4;
typedef __attribute__((ext_vector_type(4))) float  f32x4;

__device__ __forceinline__ void gload16(const void* g, const void* lds_wave_base) {
  auto gp = (const __attribute__((address_space(1))) void*)(uintptr_t)g;
  auto lp = (__attribute__((address_space(3))) void*)(uintptr_t)lds_wave_base;
  __builtin_amdgcn_global_load_lds(gp, lp, 16, 0, 0);
}

#define BAR()    asm volatile("s_barrier" ::: "memory")
#define LGKM0()  do { asm volatile("s_waitcnt lgkmcnt(0)" ::: "memory"); \
                      __builtin_amdgcn_sched_barrier(0); } while (0)
#define SCHEDB() __builtin_amdgcn_sched_barrier(0)

// ---- mask dtype probe ------------------------------------------------------
__device__ __forceinline__ void detect_mask(const void* mask, int t, int* okI, int* okF) {
  const unsigned int* mi = (const unsigned int*)mask;
  int bad_i = 0, bad_f = 0;
  for (int idx = t; idx < 1024; idx += 256) {
    unsigned v = mi[idx];
    bad_i |= !(v == 0u || v == 1u);
    bad_f |= !(v == 0u || v == 0x3f800000u);
  }
  if (bad_i) *okI = 0;
  if (bad_f) *okF = 0;
}
__device__ __forceinline__ bool read_mask(const void* mask, int n, int okI, int okF) {
  if (okI) return ((const int*)mask)[n] != 0;
  if (okF) return ((const float*)mask)[n] != 0.0f;
  return ((const unsigned char*)mask)[n] != 0;
}

// ---------------------------------------------------------------------------
// prepAll: [0,I_DIM): Wcat row; [I_DIM,+88): W88b; [+88,+132): W44b;
//          [+132,+132+H_DIM): Wda row.
// ---------------------------------------------------------------------------
__global__ __launch_bounds__(256)
void prepAll(const float* __restrict__ Wg, const float* __restrict__ Wu,
             const float* __restrict__ Wd,
             const float* __restrict__ vBg, const float* __restrict__ tmBg,
             const float* __restrict__ vBu, const float* __restrict__ tmBu,
             const float* __restrict__ vBd, const float* __restrict__ tmBd,
             const float* __restrict__ vAg, const float* __restrict__ tmAg, const float* __restrict__ rg,
             const float* __restrict__ vAu, const float* __restrict__ tmAu, const float* __restrict__ ru,
             const float* __restrict__ vAd, const float* __restrict__ tmAd, const float* __restrict__ rd,
             __bf16* __restrict__ Wcat, __bf16* __restrict__ Wda,
             __bf16* __restrict__ W88b, __bf16* __restrict__ W44b) {
  int b = blockIdx.x, t = threadIdx.x;
  if (b < I_DIM) {
    int i = b;
    int grp = i >> 7, within = i & 127;
    const float4* g4 = (const float4*)(Wg + (size_t)i * H_DIM);
    const float4* u4 = (const float4*)(Wu + (size_t)i * H_DIM);
    __bf16* og = Wcat + (size_t)(grp * 256 + within) * K1P;
    __bf16* ou = Wcat + (size_t)(grp * 256 + 128 + within) * K1P;
    for (int c = t; c < H_DIM / 4; c += 256) {
      float4 v = g4[c];
      bf16x4 bb = {(__bf16)v.x, (__bf16)v.y, (__bf16)v.z, (__bf16)v.w};
      *(bf16x4*)(og + c * 4) = bb;
      v = u4[c];
      bf16x4 b2 = {(__bf16)v.x, (__bf16)v.y, (__bf16)v.z, (__bf16)v.w};
      *(bf16x4*)(ou + c * 4) = b2;
    }
    if (t < 128) {
      float gv = 0.f, uv = 0.f;
      if (t < 8) gv = 2.f * vBg[i * R_RANK + t];
      else if (t < 40) { int e = (t - 8) >> 3, r = (t - 8) & 7;
        gv = 2.f * tmBg[((size_t)e * I_DIM + i) * R_RANK + r]; }
      if (t >= 40 && t < 48) uv = 2.f * vBu[i * R_RANK + (t - 40)];
      else if (t >= 48 && t < 80) { int e = (t - 48) >> 3, r = (t - 48) & 7;
        uv = 2.f * tmBu[((size_t)e * I_DIM + i) * R_RANK + r]; }
      og[H_DIM + t] = (__bf16)gv;
      ou[H_DIM + t] = (__bf16)uv;
    }
  } else if (b < I_DIM + 88) {
    int r = b - I_DIM;
    const float* src;
    if      (r <  8) src = vAg  + (size_t)r * H_DIM;
    else if (r < 40) src = tmAg + (size_t)(r - 8) * H_DIM;
    else if (r < 44) src = rg   + (size_t)(r - 40) * H_DIM;
    else if (r < 52) src = vAu  + (size_t)(r - 44) * H_DIM;
    else if (r < 84) src = tmAu + (size_t)(r - 52) * H_DIM;
    else             src = ru   + (size_t)(r - 84) * H_DIM;
    __bf16* dst = W88b + (size_t)r * H_DIM;
    for (int c = t; c < H_DIM / 4; c += 256) {
      float4 v = ((const float4*)src)[c];
      bf16x4 bb = {(__bf16)v.x, (__bf16)v.y, (__bf16)v.z, (__bf16)v.w};
      *(bf16x4*)(dst + c * 4) = bb;
    }
  } else if (b < I_DIM + 132) {
    int r = b - I_DIM - 88;
    const float* src = (r < 8)  ? vAd  + (size_t)r * I_DIM
                     : (r < 40) ? tmAd + (size_t)(r - 8) * I_DIM
                                : rd   + (size_t)(r - 40) * I_DIM;
    __bf16* dst = W44b + (size_t)r * I_DIM;
    for (int c = t; c < I_DIM / 4; c += 256) {
      float4 v = ((const float4*)src)[c];
      bf16x4 bb = {(__bf16)v.x, (__bf16)v.y, (__bf16)v.z, (__bf16)v.w};
      *(bf16x4*)(dst + c * 4) = bb;
    }
  } else {
    int o = b - I_DIM - 132;
    const float4* w4 = (const float4*)(Wd + (size_t)o * I_DIM);
    __bf16* orow = Wda + (size_t)o * K2P;
    for (int c = t; c < I_DIM / 4; c += 256) {
      float4 v = w4[c];
      bf16x4 bb = {(__bf16)v.x, (__bf16)v.y, (__bf16)v.z, (__bf16)v.w};
      *(bf16x4*)(orow + c * 4) = bb;
    }
    if (t < 128) {
      float v = 0.f;
      if (t < 8) v = 2.f * vBd[o * R_RANK + t];
      else if (t < 40) { int e = (t - 8) >> 3, r = (t - 8) & 7;
        v = 2.f * tmBd[((size_t)e * H_DIM + o) * R_RANK + r]; }
      orow[I_DIM + t] = (__bf16)v;
    }
  }
}

// ---------------------------------------------------------------------------
// prep_x: bf16(x) + 88 skinny dots (grouped 4-row, bf16 weights) + softmax
// ---------------------------------------------------------------------------
__global__ __launch_bounds__(256)
void prep_x(const float* __restrict__ x, const void* __restrict__ mask,
            const __bf16* __restrict__ W88b, __bf16* __restrict__ Xaug) {
  __shared__ __align__(16) float sx[4][H_DIM];
  __shared__ float dots[4][88];
  __shared__ int okI, okF;
  int t = threadIdx.x, n0 = blockIdx.x * 4;
  if (t == 0) { okI = 1; okF = 1; }
  __syncthreads();
  detect_mask(mask, t, &okI, &okF);
  for (int tok = 0; tok < 4; ++tok) {
    const float4* xr = (const float4*)(x + (size_t)(n0 + tok) * H_DIM);
    __bf16* orow = Xaug + (size_t)(n0 + tok) * K1P;
    for (int c = t; c < H_DIM / 4; c += 256) {
      float4 v = xr[c];
      *(float4*)&sx[tok][c * 4] = v;
      bf16x4 b = {(__bf16)v.x, (__bf16)v.y, (__bf16)v.z, (__bf16)v.w};
      *(bf16x4*)(orow + c * 4) = b;
    }
  }
  __syncthreads();
  int wv = t >> 6, ln = t & 63;
  for (int gi = 0; gi < 6; ++gi) {
    int g = wv + gi * 4;
    if (g >= 22) break;
    int i0 = g * 4;
    const __bf16* base = W88b + (size_t)i0 * H_DIM;
    float acc[4][4];
#pragma unroll
    for (int ii = 0; ii < 4; ++ii)
#pragma unroll
      for (int tk = 0; tk < 4; ++tk) acc[ii][tk] = 0.f;
    for (int j = 0; j < H_DIM / 256; ++j) {
      int h = j * 256 + ln * 4;
      float4 v0 = *(const float4*)&sx[0][h];
      float4 v1 = *(const float4*)&sx[1][h];
      float4 v2 = *(const float4*)&sx[2][h];
      float4 v3 = *(const float4*)&sx[3][h];
#pragma unroll
      for (int ii = 0; ii < 4; ++ii) {
        bf16x4 wb = *(const bf16x4*)(base + (size_t)ii * H_DIM + h);
        float wx = (float)wb[0], wy = (float)wb[1], wz = (float)wb[2], ww = (float)wb[3];
        acc[ii][0] = fmaf(v0.x, wx, fmaf(v0.y, wy, fmaf(v0.z, wz, fmaf(v0.w, ww, acc[ii][0]))));
        acc[ii][1] = fmaf(v1.x, wx, fmaf(v1.y, wy, fmaf(v1.z, wz, fmaf(v1.w, ww, acc[ii][1]))));
        acc[ii][2] = fmaf(v2.x, wx, fmaf(v2.y, wy, fmaf(v2.z, wz, fmaf(v2.w, ww, acc[ii][2]))));
        acc[ii][3] = fmaf(v3.x, wx, fmaf(v3.y, wy, fmaf(v3.z, wz, fmaf(v3.w, ww, acc[ii][3]))));
      }
    }
#pragma unroll
    for (int ii = 0; ii < 4; ++ii) {
#pragma unroll
      for (int tk = 0; tk < 4; ++tk) {
        float a = acc[ii][tk];
        for (int s = 32; s > 0; s >>= 1) a += __shfl_xor(a, s);
        if (ln == 0) dots[tk][i0 + ii] = a;
      }
    }
  }
  __syncthreads();
  for (int pass = 0; pass < 2; ++pass) {
    int tok = (t >> 7) + pass * 2;
    int s = t & 127;
    const float* dd = dots[tok];
    bool img = read_mask(mask, n0 + tok, okI, okF);
    float c = 0.f;
    if (s < 80) {
      if (s < 40) {
        if (img) { if (s < 8) c = dd[s]; }
        else if (s >= 8) {
          float l0 = dd[40], l1 = dd[41], l2 = dd[42], l3 = dd[43];
          float mx = fmaxf(fmaxf(l0, l1), fmaxf(l2, l3));
          float e0 = __expf(l0 - mx), e1 = __expf(l1 - mx), e2 = __expf(l2 - mx), e3 = __expf(l3 - mx);
          float inv = 1.f / (e0 + e1 + e2 + e3);
          int e = (s - 8) >> 3;
          float ge = (e == 0 ? e0 : e == 1 ? e1 : e == 2 ? e2 : e3) * inv;
          c = ge * dd[s];
        }
      } else {
        int s2 = s - 40;
        if (img) { if (s2 < 8) c = dd[44 + s2]; }
        else if (s2 >= 8) {
          float l0 = dd[84], l1 = dd[85], l2 = dd[86], l3 = dd[87];
          float mx = fmaxf(fmaxf(l0, l1), fmaxf(l2, l3));
          float e0 = __expf(l0 - mx), e1 = __expf(l1 - mx), e2 = __expf(l2 - mx), e3 = __expf(l3 - mx);
          float inv = 1.f / (e0 + e1 + e2 + e3);
          int e = (s2 - 8) >> 3;
          float ge = (e == 0 ? e0 : e == 1 ? e1 : e == 2 ? e2 : e3) * inv;
          c = ge * dd[44 + s2];
        }
      }
    }
    Xaug[(size_t)(n0 + tok) * K1P + H_DIM + s] = (__bf16)c;
  }
}

// ---------------------------------------------------------------------------
// prep_x2: 512 threads, 2 tokens/block (44KB LDS -> 3 blocks/CU), grouped dots
// ---------------------------------------------------------------------------
__global__ __launch_bounds__(512)
void prep_x2(const void* __restrict__ mask, const __bf16* __restrict__ W44b,
             __bf16* __restrict__ X2) {
  __shared__ __align__(16) __bf16 si[2][I_DIM];
  __shared__ float dots[2][44];
  __shared__ int okI, okF;
  int t = threadIdx.x, n0 = blockIdx.x * 2;
  if (t == 0) { okI = 1; okF = 1; }
  __syncthreads();
  if (t < 256) detect_mask(mask, t, &okI, &okF);
  for (int tok = 0; tok < 2; ++tok) {
    const bf16x8* xr = (const bf16x8*)(X2 + (size_t)(n0 + tok) * K2P);
    bf16x8* srow = (bf16x8*)&si[tok][0];
    for (int c = t; c < I_DIM / 8; c += 512) srow[c] = xr[c];
  }
  __syncthreads();
  int wv = t >> 6, ln = t & 63;
  const bf16x8* s0 = (const bf16x8*)&si[0][0];
  const bf16x8* s1 = (const bf16x8*)&si[1][0];
  for (int gi = 0; gi < 2; ++gi) {
    int g = wv + gi * 8;
    if (g >= 11) break;
    int i0 = g * 4;
    const __bf16* base = W44b + (size_t)i0 * I_DIM;
    float acc[4][2];
#pragma unroll
    for (int ii = 0; ii < 4; ++ii) { acc[ii][0] = 0.f; acc[ii][1] = 0.f; }
    for (int j = 0; j < 22; ++j) {
      int ch = j * 64 + ln;
      if (ch < I_DIM / 8) {
        bf16x8 x0 = s0[ch], x1 = s1[ch];
        float xf0[8], xf1[8];
#pragma unroll
        for (int k = 0; k < 8; ++k) { xf0[k] = (float)x0[k]; xf1[k] = (float)x1[k]; }
#pragma unroll
        for (int ii = 0; ii < 4; ++ii) {
          bf16x8 wv8 = *(const bf16x8*)(base + (size_t)ii * I_DIM + ch * 8);
          float a0 = acc[ii][0], a1 = acc[ii][1];
#pragma unroll
          for (int k = 0; k < 8; ++k) {
            float wk = (float)wv8[k];
            a0 = fmaf(xf0[k], wk, a0);
            a1 = fmaf(xf1[k], wk, a1);
          }
          acc[ii][0] = a0; acc[ii][1] = a1;
        }
      }
    }
#pragma unroll
    for (int ii = 0; ii < 4; ++ii) {
#pragma unroll
      for (int tk = 0; tk < 2; ++tk) {
        float a = acc[ii][tk];
        for (int s = 32; s > 0; s >>= 1) a += __shfl_xor(a, s);
        if (ln == 0) dots[tk][i0 + ii] = a;
      }
    }
  }
  __syncthreads();
  if (t < 256) {
    int tok = t >> 7, s = t & 127;
    const float* dd = dots[tok];
    bool img = read_mask(mask, n0 + tok, okI, okF);
    float c = 0.f;
    if (s < 40) {
      if (img) { if (s < 8) c = dd[s]; }
      else if (s >= 8) {
        float l0 = dd[40], l1 = dd[41], l2 = dd[42], l3 = dd[43];
        float mx = fmaxf(fmaxf(l0, l1), fmaxf(l2, l3));
        float e0 = __expf(l0 - mx), e1 = __expf(l1 - mx), e2 = __expf(l2 - mx), e3 = __expf(l3 - mx);
        float inv = 1.f / (e0 + e1 + e2 + e3);
        int e = (s - 8) >> 3;
        float ge = (e == 0 ? e0 : e == 1 ? e1 : e == 2 ? e2 : e3) * inv;
        c = ge * dd[s];
      }
    }
    X2[(size_t)(n0 + tok) * K2P + I_DIM + s] = (__bf16)c;
  }
}

// ---------------------------------------------------------------------------
// 256x256 BK=64 8-wave phased GEMM — full shadow rotation (r11 schedule),
// K-loop unrolled 2x (static double-buffer addressing).
// ---------------------------------------------------------------------------
template<int MH, int NH>
__device__ __forceinline__ void mfmaq(f32x4 (&acc)[8][4], const bf16x8 (&av)[4][2],
                                      const bf16x8 (&bv)[2][2]) {
#pragma unroll
  for (int kk = 0; kk < 2; ++kk)
#pragma unroll
    for (int j = 0; j < 2; ++j)
#pragma unroll
      for (int i = 0; i < 4; ++i)
        acc[MH * 4 + i][NH * 2 + j] = __builtin_amdgcn_mfma_f32_16x16x32_bf16(
            av[i][kk], bv[j][kk], acc[MH * 4 + i][NH * 2 + j], 0, 0, 0);
}

template<int KS, int NT, int GN, typename OutT, int OSTR, int EPI, int MODE>
__global__ __launch_bounds__(512, 2)
void gemm256(const __bf16* __restrict__ A, const __bf16* __restrict__ Bm,
             OutT* __restrict__ C) {
  __shared__ __align__(16) char lds[131072];

  int t = threadIdx.x;
  int w = t >> 6, l = t & 63;
  int wm = w >> 2, wn = w & 3;
  int lrow = l & 15, kq = l >> 4;

  int nwg = gridDim.x, bid = blockIdx.x;
  int tm, tn;
  if constexpr (MODE == 1) {           // 16x16 grid: 8x4 rectangle per XCD
    int xx = bid & 7, ii = bid >> 3;
    tm = ((xx & 1) << 3) | (ii & 7);
    tn = ((xx >> 1) << 2) | (ii >> 3);
  } else if constexpr (MODE == 2) {    // L3 supertile: 256-block windows = 16tm x 16tn
    constexpr int FULL = (GN / 16) * 256;
    if (bid < FULL) { int s = bid >> 8, ww = bid & 255; tm = ww & 15; tn = s * 16 + (ww >> 4); }
    else            { int ww = bid - FULL; tm = ww & 15; tn = (GN / 16) * 16 + (ww >> 4); }
  } else {
    int swz = (bid & 7) * (nwg >> 3) + (bid >> 3);
    tm = swz / GN; tn = swz % GN;
  }
  int m0 = tm * 256, n0 = tn * 256;

  // staging: per-lane inverse-swizzled global source; linear LDS dest
  int grow = (t >> 3) & 7;
  int gcole = ((t & 7) ^ grow) << 3;
  const __bf16* gA0 = A  + (size_t)(m0 + w * 8 + grow) * KS + gcole;
  const __bf16* gB0 = Bm + (size_t)(n0 + w * 8 + grow) * KS + gcole;
  char* ldsA0 = lds + w * 1024;
  char* ldsB0 = lds + 32768 + w * 1024;

  auto stageA = [&](int buf, int tt, int c) {
    gload16(gA0 + (size_t)c * (64 * KS) + (size_t)tt * 64,
            ldsA0 + buf * 65536 + c * 8192);
  };
  auto stageB = [&](int buf, int tt, int c) {
    gload16(gB0 + (size_t)c * (64 * KS) + (size_t)tt * 64,
            ldsB0 + buf * 65536 + c * 8192);
  };

  // swizzled ds_read addressing
  int aBase = (wm * 128 + lrow) * 128;
  int bBase = (wn * 64 + lrow) * 128;
  int sw    = (lrow & 7) << 4;
  int col0  = (kq * 16) ^ sw;
  int col1  = (64 + kq * 16) ^ sw;

  f32x4 acc[8][4];
#pragma unroll
  for (int i = 0; i < 8; ++i)
#pragma unroll
    for (int j = 0; j < 4; ++j) acc[i][j] = (f32x4){0.f, 0.f, 0.f, 0.f};

  // prologue: tiles 0 -> buf0, 1 -> buf1; pre-read b0(0) + aLo(0) from buf0
#pragma unroll
  for (int c = 0; c < 4; ++c) { stageA(0, 0, c); stageB(0, 0, c); }
#pragma unroll
  for (int c = 0; c < 4; ++c) { stageA(1, 1, c); stageB(1, 1, c); }
  asm volatile("s_waitcnt vmcnt(8)" ::: "memory");
  BAR();

  bf16x8 aF[4][2], b0v[2][2];
  {
    const char* sa0 = lds;
    const char* sb0 = lds + 32768;
#pragma unroll
    for (int j = 0; j < 2; ++j) {
      b0v[j][0] = *(const bf16x8*)(sb0 + bBase + j * 2048 + col0);
      b0v[j][1] = *(const bf16x8*)(sb0 + bBase + j * 2048 + col1);
    }
#pragma unroll
    for (int i = 0; i < 4; ++i) {
      aF[i][0] = *(const bf16x8*)(sa0 + aBase + i * 2048 + col0);
      aF[i][1] = *(const bf16x8*)(sa0 + aBase + i * 2048 + col1);
    }
  }

#pragma unroll 2
  for (int tt = 0; tt < NT; ++tt) {
    int cur = tt & 1;
    const char* sa  = lds + (cur ? 65536 : 0);
    const char* sb  = sa + 32768;
    const char* saN = lds + (cur ? 0 : 65536);           // next tile's A buffer
    const char* sbN = saN + 32768;                       // next tile's B buffer
    int t2 = tt + 2;
    bool st   = t2 < NT;
    bool more = tt + 1 < NT;
    bf16x8 aH[4][2], b1v[2][2];

    // P1: lgkm0 confirms P4-shadow reads; issue b1(4) into Q00's shadow; Q00
    BAR(); LGKM0();
#pragma unroll
    for (int j = 0; j < 2; ++j) {
      b1v[j][0] = *(const bf16x8*)(sb + bBase + (2 + j) * 2048 + col0);
      b1v[j][1] = *(const bf16x8*)(sb + bBase + (2 + j) * 2048 + col1);
    }
    __builtin_amdgcn_s_setprio(1);
    mfmaq<0, 0>(acc, aF, b0v);
    __builtin_amdgcn_s_setprio(0);
    BAR();

    // P2: stage A[t+2] chunks 0,2; lgkm0 (b1 drained); issue aHi(8); Q01
    if (st) { stageA(cur, t2, 0); stageA(cur, t2, 2); }
    BAR(); LGKM0();
#pragma unroll
    for (int i = 0; i < 4; ++i) {
      aH[i][0] = *(const bf16x8*)(sa + aBase + (4 + i) * 2048 + col0);
      aH[i][1] = *(const bf16x8*)(sa + aBase + (4 + i) * 2048 + col1);
    }
    __builtin_amdgcn_s_setprio(1);
    mfmaq<0, 1>(acc, aF, b1v);
    __builtin_amdgcn_s_setprio(0);
    BAR();

    // P3: stage B[t+2] chunks 0,1; lgkm0 (aHi drained); Q10
    if (st) { stageB(cur, t2, 0); stageB(cur, t2, 1); }
    BAR(); LGKM0();
    __builtin_amdgcn_s_setprio(1);
    mfmaq<1, 0>(acc, aH, b0v);
    __builtin_amdgcn_s_setprio(0);
    BAR();

    // P4: stage B2,B3,A1,A3; counted vmcnt validates buf^1; read b0(t+1)
    //     AND aLo(t+1) into Q11's shadow (drain across 2 barriers into P1)
    if (st) { stageB(cur, t2, 2); stageB(cur, t2, 3);
              stageA(cur, t2, 1); stageA(cur, t2, 3); }
    if (st) asm volatile("s_waitcnt vmcnt(8)" ::: "memory");
    else    asm volatile("s_waitcnt vmcnt(0)" ::: "memory");
    SCHEDB();                       // pin: buf^1 reads issue AFTER the vmcnt
    if (more) {
#pragma unroll
      for (int j = 0; j < 2; ++j) {
        b0v[j][0] = *(const bf16x8*)(sbN + bBase + j * 2048 + col0);
        b0v[j][1] = *(const bf16x8*)(sbN + bBase + j * 2048 + col1);
      }
#pragma unroll
      for (int i = 0; i < 4; ++i) {
        aF[i][0] = *(const bf16x8*)(saN + aBase + i * 2048 + col0);
        aF[i][1] = *(const bf16x8*)(saN + aBase + i * 2048 + col1);
      }
    }
    __builtin_amdgcn_s_setprio(1);
    mfmaq<1, 1>(acc, aH, b1v);
    __builtin_amdgcn_s_setprio(0);
    BAR();
  }

  if constexpr (EPI == 0) {
    int r0 = m0 + wm * 128 + kq * 4;
    int c0 = n0 + wn * 64 + lrow;
#pragma unroll
    for (int mi = 0; mi < 8; ++mi) {
#pragma unroll
      for (int q = 0; q < 4; ++q) {
        OutT* p = C + (size_t)(r0 + mi * 16 + q) * OSTR + c0;
#pragma unroll
        for (int ni = 0; ni < 4; ++ni) p[ni * 16] = (OutT)acc[mi][ni][q];
      }
    }
  } else {
    // Parallel silu fusion (r4 verified): gate wave (wn<2) pairs with up wave
    // (wn+2); rows split mi0-3 / mi4-7; 2-way max conflict exchange.
    float* xch = (float*)lds;
    bool isGate = (wn < 2);
    int p = wm * 2 + (wn & 1);
    float* mybuf = xch + (size_t)p * 8192 + (isGate ? 4096 : 0);
#pragma unroll
    for (int mi = 0; mi < 4; ++mi) {
      int msrc = isGate ? (4 + mi) : mi;
#pragma unroll
      for (int q = 0; q < 4; ++q) {
        int r = mi * 16 + kq * 4 + q;
        int key = (r >> 2) & 3;
#pragma unroll
        for (int ni = 0; ni < 4; ++ni) {
          int c = (ni * 16 + lrow) ^ (key << 4);
          mybuf[r * 64 + c] = acc[msrc][ni][q];
        }
      }
    }
    __syncthreads();
    const float* pbuf = xch + (size_t)p * 8192 + (isGate ? 0 : 4096);
    int mbase = isGate ? 0 : 4;
    int rowoff = isGate ? 0 : 64;
#pragma unroll
    for (int mi = 0; mi < 4; ++mi) {
#pragma unroll
      for (int q = 0; q < 4; ++q) {
        int r = mi * 16 + kq * 4 + q;
        int key = (r >> 2) & 3;
        int row = m0 + wm * 128 + rowoff + r;
        OutT* orow = C + (size_t)row * OSTR + tn * 128 + (wn & 1) * 64 + lrow;
#pragma unroll
        for (int ni = 0; ni < 4; ++ni) {
          int c = (ni * 16 + lrow) ^ (key << 4);
          float o = pbuf[r * 64 + c];
          float g = isGate ? acc[mbase + mi][ni][q] : o;
          float u = isGate ? o : acc[mbase + mi][ni][q];
          orow[ni * 16] = (OutT)(g / (1.f + __expf(-g)) * u);
        }
      }
    }
  }
}

// ---------------------------------------------------------------------------
extern "C" void kernel_launch(void* const* d_in, const int* in_sizes, int n_in,
                              void* d_out, int out_size, void* d_ws, size_t ws_size,
                              hipStream_t stream) {
  const float* x    = (const float*)d_in[0];
  const void*  mask = d_in[1];
  const float* Wg   = (const float*)d_in[2];
  const float* Wu   = (const float*)d_in[3];
  const float* Wd   = (const float*)d_in[4];
  const float* vAg  = (const float*)d_in[5];
  const float* vBg  = (const float*)d_in[6];
  const float* vAu  = (const float*)d_in[7];
  const float* vBu  = (const float*)d_in[8];
  const float* vAd  = (const float*)d_in[9];
  const float* vBd  = (const float*)d_in[10];
  const float* rg   = (const float*)d_in[11];
  const float* tmAg = (const float*)d_in[12];
  const float* tmBg = (const float*)d_in[13];
  const float* ru   = (const float*)d_in[14];
  const float* tmAu = (const float*)d_in[15];
  const float* tmBu = (const float*)d_in[16];
  const float* rd   = (const float*)d_in[17];
  const float* tmAd = (const float*)d_in[18];
  const float* tmBd = (const float*)d_in[19];

  // workspace layout (bytes), total 403,046,400:
  //   Xaug 0 .. 34,603,008
  //   Wcat 34,603,008 .. 220,594,176   (22016 x 4224 bf16, interleaved g/u)
  //   X2   220,594,176 .. 311,820,288  (4096 x 11136 bf16)
  //   Wda  311,820,288 .. 403,046,400  (4096 x 11136 bf16)
  // transient stashes in d_out (dead until gemm2 overwrites it completely):
  //   W88b = d_out + 0        (721 KB, consumed by prep_x)
  //   W44b = d_out + 1 MiB    (969 KB, consumed by prep_x2)
  char* ws = (char*)d_ws;
  __bf16* Xaug = (__bf16*)(ws);
  __bf16* Wcat = (__bf16*)(ws + 34603008);
  __bf16* X2   = (__bf16*)(ws + 220594176);
  __bf16* Wda  = (__bf16*)(ws + 311820288);
  __bf16* W88b = (__bf16*)d_out;
  __bf16* W44b = (__bf16*)((char*)d_out + 1048576);

  prepAll<<<I_DIM + 132 + H_DIM, 256, 0, stream>>>(
      Wg, Wu, Wd, vBg, tmBg, vBu, tmBu, vBd, tmBd,
      vAg, tmAg, rg, vAu, tmAu, ru, vAd, tmAd, rd,
      Wcat, Wda, W88b, W44b);
  prep_x<<<N_TOK / 4, 256, 0, stream>>>(x, mask, W88b, Xaug);

  // GEMM1 fused: grid 16*86 = 1376; L3 supertile map; silu(g)*u into X2
  gemm256<K1P, K1P / 64, 86, __bf16, K2P, 1, 2>
      <<<(N_TOK / 256) * 86, 512, 0, stream>>>(Xaug, Wcat, X2);

  prep_x2<<<N_TOK / 2, 512, 0, stream>>>(mask, W44b, X2);

  // GEMM2: grid 16*16 = 256, rectangle XCD map
  gemm256<K2P, K2P / 64, H_DIM / 256, float, H_DIM, 0, 1>
      <<<(N_TOK / 256) * (H_DIM / 256), 512, 0, stream>>>(X2, Wda, (float*)d_out);
}

// Round 15
// 1414.942 us; speedup vs baseline: 1.7096x; 1.7096x over previous
//
#include <hip/hip_runtime.h>
#include <hip/hip_bf16.h>
#include <stdint.h>

// ---------------------------------------------------------------------------
// MoDEChameleonMLP, round 15: REVERT to round-13 exactly (verified 1420.7us,
// twice). r14's unroll-2 doubled live ranges -> scratch spill (+72MB writes,
// MfmaUtil 47->22). The r13 structure is the verified optimum: shadow-rotated
// 4-phase BK=64 schedule, L3 supertile (gemm1), rectangle XCD map (gemm2),
// fused silu epilogue, bf16 grouped-dot preps.
// ---------------------------------------------------------------------------

#define H_DIM 4096
#define I_DIM 11008
#define N_TOK 4096
#define R_RANK 8
#define K1P 4224
#define K2P 11136

typedef __attribute__((ext_vector_type(8))) __bf16 bf16x8;
typedef __attribute__((ext_vector_type(4))) __bf16 bf16x4;
typedef __attribute__((ext_vector_type(4))) float  f32x4;

__device__ __forceinline__ void gload16(const void* g, const void* lds_wave_base) {
  auto gp = (const __attribute__((address_space(1))) void*)(uintptr_t)g;
  auto lp = (__attribute__((address_space(3))) void*)(uintptr_t)lds_wave_base;
  __builtin_amdgcn_global_load_lds(gp, lp, 16, 0, 0);
}

#define BAR()    asm volatile("s_barrier" ::: "memory")
#define LGKM0()  do { asm volatile("s_waitcnt lgkmcnt(0)" ::: "memory"); \
                      __builtin_amdgcn_sched_barrier(0); } while (0)
#define SCHEDB() __builtin_amdgcn_sched_barrier(0)

// ---- mask dtype probe ------------------------------------------------------
__device__ __forceinline__ void detect_mask(const void* mask, int t, int* okI, int* okF) {
  const unsigned int* mi = (const unsigned int*)mask;
  int bad_i = 0, bad_f = 0;
  for (int idx = t; idx < 1024; idx += 256) {
    unsigned v = mi[idx];
    bad_i |= !(v == 0u || v == 1u);
    bad_f |= !(v == 0u || v == 0x3f800000u);
  }
  if (bad_i) *okI = 0;
  if (bad_f) *okF = 0;
}
__device__ __forceinline__ bool read_mask(const void* mask, int n, int okI, int okF) {
  if (okI) return ((const int*)mask)[n] != 0;
  if (okF) return ((const float*)mask)[n] != 0.0f;
  return ((const unsigned char*)mask)[n] != 0;
}

// ---------------------------------------------------------------------------
// prepAll: [0,I_DIM): Wcat row; [I_DIM,+88): W88b; [+88,+132): W44b;
//          [+132,+132+H_DIM): Wda row.
// ---------------------------------------------------------------------------
__global__ __launch_bounds__(256)
void prepAll(const float* __restrict__ Wg, const float* __restrict__ Wu,
             const float* __restrict__ Wd,
             const float* __restrict__ vBg, const float* __restrict__ tmBg,
             const float* __restrict__ vBu, const float* __restrict__ tmBu,
             const float* __restrict__ vBd, const float* __restrict__ tmBd,
             const float* __restrict__ vAg, const float* __restrict__ tmAg, const float* __restrict__ rg,
             const float* __restrict__ vAu, const float* __restrict__ tmAu, const float* __restrict__ ru,
             const float* __restrict__ vAd, const float* __restrict__ tmAd, const float* __restrict__ rd,
             __bf16* __restrict__ Wcat, __bf16* __restrict__ Wda,
             __bf16* __restrict__ W88b, __bf16* __restrict__ W44b) {
  int b = blockIdx.x, t = threadIdx.x;
  if (b < I_DIM) {
    int i = b;
    int grp = i >> 7, within = i & 127;
    const float4* g4 = (const float4*)(Wg + (size_t)i * H_DIM);
    const float4* u4 = (const float4*)(Wu + (size_t)i * H_DIM);
    __bf16* og = Wcat + (size_t)(grp * 256 + within) * K1P;
    __bf16* ou = Wcat + (size_t)(grp * 256 + 128 + within) * K1P;
    for (int c = t; c < H_DIM / 4; c += 256) {
      float4 v = g4[c];
      bf16x4 bb = {(__bf16)v.x, (__bf16)v.y, (__bf16)v.z, (__bf16)v.w};
      *(bf16x4*)(og + c * 4) = bb;
      v = u4[c];
      bf16x4 b2 = {(__bf16)v.x, (__bf16)v.y, (__bf16)v.z, (__bf16)v.w};
      *(bf16x4*)(ou + c * 4) = b2;
    }
    if (t < 128) {
      float gv = 0.f, uv = 0.f;
      if (t < 8) gv = 2.f * vBg[i * R_RANK + t];
      else if (t < 40) { int e = (t - 8) >> 3, r = (t - 8) & 7;
        gv = 2.f * tmBg[((size_t)e * I_DIM + i) * R_RANK + r]; }
      if (t >= 40 && t < 48) uv = 2.f * vBu[i * R_RANK + (t - 40)];
      else if (t >= 48 && t < 80) { int e = (t - 48) >> 3, r = (t - 48) & 7;
        uv = 2.f * tmBu[((size_t)e * I_DIM + i) * R_RANK + r]; }
      og[H_DIM + t] = (__bf16)gv;
      ou[H_DIM + t] = (__bf16)uv;
    }
  } else if (b < I_DIM + 88) {
    int r = b - I_DIM;
    const float* src;
    if      (r <  8) src = vAg  + (size_t)r * H_DIM;
    else if (r < 40) src = tmAg + (size_t)(r - 8) * H_DIM;
    else if (r < 44) src = rg   + (size_t)(r - 40) * H_DIM;
    else if (r < 52) src = vAu  + (size_t)(r - 44) * H_DIM;
    else if (r < 84) src = tmAu + (size_t)(r - 52) * H_DIM;
    else             src = ru   + (size_t)(r - 84) * H_DIM;
    __bf16* dst = W88b + (size_t)r * H_DIM;
    for (int c = t; c < H_DIM / 4; c += 256) {
      float4 v = ((const float4*)src)[c];
      bf16x4 bb = {(__bf16)v.x, (__bf16)v.y, (__bf16)v.z, (__bf16)v.w};
      *(bf16x4*)(dst + c * 4) = bb;
    }
  } else if (b < I_DIM + 132) {
    int r = b - I_DIM - 88;
    const float* src = (r < 8)  ? vAd  + (size_t)r * I_DIM
                     : (r < 40) ? tmAd + (size_t)(r - 8) * I_DIM
                                : rd   + (size_t)(r - 40) * I_DIM;
    __bf16* dst = W44b + (size_t)r * I_DIM;
    for (int c = t; c < I_DIM / 4; c += 256) {
      float4 v = ((const float4*)src)[c];
      bf16x4 bb = {(__bf16)v.x, (__bf16)v.y, (__bf16)v.z, (__bf16)v.w};
      *(bf16x4*)(dst + c * 4) = bb;
    }
  } else {
    int o = b - I_DIM - 132;
    const float4* w4 = (const float4*)(Wd + (size_t)o * I_DIM);
    __bf16* orow = Wda + (size_t)o * K2P;
    for (int c = t; c < I_DIM / 4; c += 256) {
      float4 v = w4[c];
      bf16x4 bb = {(__bf16)v.x, (__bf16)v.y, (__bf16)v.z, (__bf16)v.w};
      *(bf16x4*)(orow + c * 4) = bb;
    }
    if (t < 128) {
      float v = 0.f;
      if (t < 8) v = 2.f * vBd[o * R_RANK + t];
      else if (t < 40) { int e = (t - 8) >> 3, r = (t - 8) & 7;
        v = 2.f * tmBd[((size_t)e * H_DIM + o) * R_RANK + r]; }
      orow[I_DIM + t] = (__bf16)v;
    }
  }
}

// ---------------------------------------------------------------------------
// prep_x: bf16(x) + 88 skinny dots (grouped 4-row, bf16 weights) + softmax
// ---------------------------------------------------------------------------
__global__ __launch_bounds__(256)
void prep_x(const float* __restrict__ x, const void* __restrict__ mask,
            const __bf16* __restrict__ W88b, __bf16* __restrict__ Xaug) {
  __shared__ __align__(16) float sx[4][H_DIM];
  __shared__ float dots[4][88];
  __shared__ int okI, okF;
  int t = threadIdx.x, n0 = blockIdx.x * 4;
  if (t == 0) { okI = 1; okF = 1; }
  __syncthreads();
  detect_mask(mask, t, &okI, &okF);
  for (int tok = 0; tok < 4; ++tok) {
    const float4* xr = (const float4*)(x + (size_t)(n0 + tok) * H_DIM);
    __bf16* orow = Xaug + (size_t)(n0 + tok) * K1P;
    for (int c = t; c < H_DIM / 4; c += 256) {
      float4 v = xr[c];
      *(float4*)&sx[tok][c * 4] = v;
      bf16x4 b = {(__bf16)v.x, (__bf16)v.y, (__bf16)v.z, (__bf16)v.w};
      *(bf16x4*)(orow + c * 4) = b;
    }
  }
  __syncthreads();
  int wv = t >> 6, ln = t & 63;
  for (int gi = 0; gi < 6; ++gi) {
    int g = wv + gi * 4;
    if (g >= 22) break;
    int i0 = g * 4;
    const __bf16* base = W88b + (size_t)i0 * H_DIM;
    float acc[4][4];
#pragma unroll
    for (int ii = 0; ii < 4; ++ii)
#pragma unroll
      for (int tk = 0; tk < 4; ++tk) acc[ii][tk] = 0.f;
    for (int j = 0; j < H_DIM / 256; ++j) {
      int h = j * 256 + ln * 4;
      float4 v0 = *(const float4*)&sx[0][h];
      float4 v1 = *(const float4*)&sx[1][h];
      float4 v2 = *(const float4*)&sx[2][h];
      float4 v3 = *(const float4*)&sx[3][h];
#pragma unroll
      for (int ii = 0; ii < 4; ++ii) {
        bf16x4 wb = *(const bf16x4*)(base + (size_t)ii * H_DIM + h);
        float wx = (float)wb[0], wy = (float)wb[1], wz = (float)wb[2], ww = (float)wb[3];
        acc[ii][0] = fmaf(v0.x, wx, fmaf(v0.y, wy, fmaf(v0.z, wz, fmaf(v0.w, ww, acc[ii][0]))));
        acc[ii][1] = fmaf(v1.x, wx, fmaf(v1.y, wy, fmaf(v1.z, wz, fmaf(v1.w, ww, acc[ii][1]))));
        acc[ii][2] = fmaf(v2.x, wx, fmaf(v2.y, wy, fmaf(v2.z, wz, fmaf(v2.w, ww, acc[ii][2]))));
        acc[ii][3] = fmaf(v3.x, wx, fmaf(v3.y, wy, fmaf(v3.z, wz, fmaf(v3.w, ww, acc[ii][3]))));
      }
    }
#pragma unroll
    for (int ii = 0; ii < 4; ++ii) {
#pragma unroll
      for (int tk = 0; tk < 4; ++tk) {
        float a = acc[ii][tk];
        for (int s = 32; s > 0; s >>= 1) a += __shfl_xor(a, s);
        if (ln == 0) dots[tk][i0 + ii] = a;
      }
    }
  }
  __syncthreads();
  for (int pass = 0; pass < 2; ++pass) {
    int tok = (t >> 7) + pass * 2;
    int s = t & 127;
    const float* dd = dots[tok];
    bool img = read_mask(mask, n0 + tok, okI, okF);
    float c = 0.f;
    if (s < 80) {
      if (s < 40) {
        if (img) { if (s < 8) c = dd[s]; }
        else if (s >= 8) {
          float l0 = dd[40], l1 = dd[41], l2 = dd[42], l3 = dd[43];
          float mx = fmaxf(fmaxf(l0, l1), fmaxf(l2, l3));
          float e0 = __expf(l0 - mx), e1 = __expf(l1 - mx), e2 = __expf(l2 - mx), e3 = __expf(l3 - mx);
          float inv = 1.f / (e0 + e1 + e2 + e3);
          int e = (s - 8) >> 3;
          float ge = (e == 0 ? e0 : e == 1 ? e1 : e == 2 ? e2 : e3) * inv;
          c = ge * dd[s];
        }
      } else {
        int s2 = s - 40;
        if (img) { if (s2 < 8) c = dd[44 + s2]; }
        else if (s2 >= 8) {
          float l0 = dd[84], l1 = dd[85], l2 = dd[86], l3 = dd[87];
          float mx = fmaxf(fmaxf(l0, l1), fmaxf(l2, l3));
          float e0 = __expf(l0 - mx), e1 = __expf(l1 - mx), e2 = __expf(l2 - mx), e3 = __expf(l3 - mx);
          float inv = 1.f / (e0 + e1 + e2 + e3);
          int e = (s2 - 8) >> 3;
          float ge = (e == 0 ? e0 : e == 1 ? e1 : e == 2 ? e2 : e3) * inv;
          c = ge * dd[44 + s2];
        }
      }
    }
    Xaug[(size_t)(n0 + tok) * K1P + H_DIM + s] = (__bf16)c;
  }
}

// ---------------------------------------------------------------------------
// prep_x2: 512 threads, 2 tokens/block (44KB LDS -> 3 blocks/CU), grouped dots
// ---------------------------------------------------------------------------
__global__ __launch_bounds__(512)
void prep_x2(const void* __restrict__ mask, const __bf16* __restrict__ W44b,
             __bf16* __restrict__ X2) {
  __shared__ __align__(16) __bf16 si[2][I_DIM];
  __shared__ float dots[2][44];
  __shared__ int okI, okF;
  int t = threadIdx.x, n0 = blockIdx.x * 2;
  if (t == 0) { okI = 1; okF = 1; }
  __syncthreads();
  if (t < 256) detect_mask(mask, t, &okI, &okF);
  for (int tok = 0; tok < 2; ++tok) {
    const bf16x8* xr = (const bf16x8*)(X2 + (size_t)(n0 + tok) * K2P);
    bf16x8* srow = (bf16x8*)&si[tok][0];
    for (int c = t; c < I_DIM / 8; c += 512) srow[c] = xr[c];
  }
  __syncthreads();
  int wv = t >> 6, ln = t & 63;
  const bf16x8* s0 = (const bf16x8*)&si[0][0];
  const bf16x8* s1 = (const bf16x8*)&si[1][0];
  for (int gi = 0; gi < 2; ++gi) {
    int g = wv + gi * 8;
    if (g >= 11) break;
    int i0 = g * 4;
    const __bf16* base = W44b + (size_t)i0 * I_DIM;
    float acc[4][2];
#pragma unroll
    for (int ii = 0; ii < 4; ++ii) { acc[ii][0] = 0.f; acc[ii][1] = 0.f; }
    for (int j = 0; j < 22; ++j) {
      int ch = j * 64 + ln;
      if (ch < I_DIM / 8) {
        bf16x8 x0 = s0[ch], x1 = s1[ch];
        float xf0[8], xf1[8];
#pragma unroll
        for (int k = 0; k < 8; ++k) { xf0[k] = (float)x0[k]; xf1[k] = (float)x1[k]; }
#pragma unroll
        for (int ii = 0; ii < 4; ++ii) {
          bf16x8 wv8 = *(const bf16x8*)(base + (size_t)ii * I_DIM + ch * 8);
          float a0 = acc[ii][0], a1 = acc[ii][1];
#pragma unroll
          for (int k = 0; k < 8; ++k) {
            float wk = (float)wv8[k];
            a0 = fmaf(xf0[k], wk, a0);
            a1 = fmaf(xf1[k], wk, a1);
          }
          acc[ii][0] = a0; acc[ii][1] = a1;
        }
      }
    }
#pragma unroll
    for (int ii = 0; ii < 4; ++ii) {
#pragma unroll
      for (int tk = 0; tk < 2; ++tk) {
        float a = acc[ii][tk];
        for (int s = 32; s > 0; s >>= 1) a += __shfl_xor(a, s);
        if (ln == 0) dots[tk][i0 + ii] = a;
      }
    }
  }
  __syncthreads();
  if (t < 256) {
    int tok = t >> 7, s = t & 127;
    const float* dd = dots[tok];
    bool img = read_mask(mask, n0 + tok, okI, okF);
    float c = 0.f;
    if (s < 40) {
      if (img) { if (s < 8) c = dd[s]; }
      else if (s >= 8) {
        float l0 = dd[40], l1 = dd[41], l2 = dd[42], l3 = dd[43];
        float mx = fmaxf(fmaxf(l0, l1), fmaxf(l2, l3));
        float e0 = __expf(l0 - mx), e1 = __expf(l1 - mx), e2 = __expf(l2 - mx), e3 = __expf(l3 - mx);
        float inv = 1.f / (e0 + e1 + e2 + e3);
        int e = (s - 8) >> 3;
        float ge = (e == 0 ? e0 : e == 1 ? e1 : e == 2 ? e2 : e3) * inv;
        c = ge * dd[s];
      }
    }
    X2[(size_t)(n0 + tok) * K2P + I_DIM + s] = (__bf16)c;
  }
}

// ---------------------------------------------------------------------------
// 256x256 BK=64 8-wave phased GEMM — full shadow rotation (r11/r13 schedule):
//   prologue: pre-read b0(0) + aLo(0)
//   P1: lgkm0 (confirms P4-shadow reads); issue b1(4) [under Q00];   Q00
//   P2: stage A0,A2; lgkm0 (b1 done); issue aHi(8) [under Q01];      Q01
//   P3: stage B0,B1; lgkm0 (aHi done);                               Q10
//   P4: stage B2,B3,A1,A3; vmcnt(8|0); read b0(t+1)+aLo(t+1) [12];   Q11
// EPI=0: plain store. EPI=1: parallel silu(g)*u fusion.
// MODE=1: 8x4 rectangle per XCD. MODE=2: L3 supertile (16tm x 16tn windows).
// ---------------------------------------------------------------------------
template<int MH, int NH>
__device__ __forceinline__ void mfmaq(f32x4 (&acc)[8][4], const bf16x8 (&av)[4][2],
                                      const bf16x8 (&bv)[2][2]) {
#pragma unroll
  for (int kk = 0; kk < 2; ++kk)
#pragma unroll
    for (int j = 0; j < 2; ++j)
#pragma unroll
      for (int i = 0; i < 4; ++i)
        acc[MH * 4 + i][NH * 2 + j] = __builtin_amdgcn_mfma_f32_16x16x32_bf16(
            av[i][kk], bv[j][kk], acc[MH * 4 + i][NH * 2 + j], 0, 0, 0);
}

template<int KS, int NT, int GN, typename OutT, int OSTR, int EPI, int MODE>
__global__ __launch_bounds__(512, 2)
void gemm256(const __bf16* __restrict__ A, const __bf16* __restrict__ Bm,
             OutT* __restrict__ C) {
  __shared__ __align__(16) char lds[131072];

  int t = threadIdx.x;
  int w = t >> 6, l = t & 63;
  int wm = w >> 2, wn = w & 3;
  int lrow = l & 15, kq = l >> 4;

  int nwg = gridDim.x, bid = blockIdx.x;
  int tm, tn;
  if constexpr (MODE == 1) {           // 16x16 grid: 8x4 rectangle per XCD
    int xx = bid & 7, ii = bid >> 3;
    tm = ((xx & 1) << 3) | (ii & 7);
    tn = ((xx >> 1) << 2) | (ii >> 3);
  } else if constexpr (MODE == 2) {    // L3 supertile: 256-block windows = 16tm x 16tn
    constexpr int FULL = (GN / 16) * 256;
    if (bid < FULL) { int s = bid >> 8, ww = bid & 255; tm = ww & 15; tn = s * 16 + (ww >> 4); }
    else            { int ww = bid - FULL; tm = ww & 15; tn = (GN / 16) * 16 + (ww >> 4); }
  } else {
    int swz = (bid & 7) * (nwg >> 3) + (bid >> 3);
    tm = swz / GN; tn = swz % GN;
  }
  int m0 = tm * 256, n0 = tn * 256;

  // staging: per-lane inverse-swizzled global source; linear LDS dest
  int grow = (t >> 3) & 7;
  int gcole = ((t & 7) ^ grow) << 3;
  const __bf16* gA0 = A  + (size_t)(m0 + w * 8 + grow) * KS + gcole;
  const __bf16* gB0 = Bm + (size_t)(n0 + w * 8 + grow) * KS + gcole;
  char* ldsA0 = lds + w * 1024;
  char* ldsB0 = lds + 32768 + w * 1024;

  auto stageA = [&](int buf, int tt, int c) {
    gload16(gA0 + (size_t)c * (64 * KS) + (size_t)tt * 64,
            ldsA0 + buf * 65536 + c * 8192);
  };
  auto stageB = [&](int buf, int tt, int c) {
    gload16(gB0 + (size_t)c * (64 * KS) + (size_t)tt * 64,
            ldsB0 + buf * 65536 + c * 8192);
  };

  // swizzled ds_read addressing
  int aBase = (wm * 128 + lrow) * 128;
  int bBase = (wn * 64 + lrow) * 128;
  int sw    = (lrow & 7) << 4;
  int col0  = (kq * 16) ^ sw;
  int col1  = (64 + kq * 16) ^ sw;

  f32x4 acc[8][4];
#pragma unroll
  for (int i = 0; i < 8; ++i)
#pragma unroll
    for (int j = 0; j < 4; ++j) acc[i][j] = (f32x4){0.f, 0.f, 0.f, 0.f};

  // prologue: tiles 0 -> buf0, 1 -> buf1; pre-read b0(0) + aLo(0) from buf0
#pragma unroll
  for (int c = 0; c < 4; ++c) { stageA(0, 0, c); stageB(0, 0, c); }
#pragma unroll
  for (int c = 0; c < 4; ++c) { stageA(1, 1, c); stageB(1, 1, c); }
  asm volatile("s_waitcnt vmcnt(8)" ::: "memory");
  BAR();

  bf16x8 aF[4][2], b0v[2][2];
  {
    const char* sa0 = lds;
    const char* sb0 = lds + 32768;
#pragma unroll
    for (int j = 0; j < 2; ++j) {
      b0v[j][0] = *(const bf16x8*)(sb0 + bBase + j * 2048 + col0);
      b0v[j][1] = *(const bf16x8*)(sb0 + bBase + j * 2048 + col1);
    }
#pragma unroll
    for (int i = 0; i < 4; ++i) {
      aF[i][0] = *(const bf16x8*)(sa0 + aBase + i * 2048 + col0);
      aF[i][1] = *(const bf16x8*)(sa0 + aBase + i * 2048 + col1);
    }
  }

  int cur = 0;
  for (int tt = 0; tt < NT; ++tt, cur ^= 1) {
    const char* sa  = lds + (cur ? 65536 : 0);
    const char* sb  = sa + 32768;
    const char* saN = lds + (cur ? 0 : 65536);           // next tile's A buffer
    const char* sbN = saN + 32768;                       // next tile's B buffer
    int t2 = tt + 2;
    bool st   = t2 < NT;
    bool more = tt + 1 < NT;
    bf16x8 aH[4][2], b1v[2][2];

    // P1: lgkm0 confirms P4-shadow reads; issue b1(4) into Q00's shadow; Q00
    BAR(); LGKM0();
#pragma unroll
    for (int j = 0; j < 2; ++j) {
      b1v[j][0] = *(const bf16x8*)(sb + bBase + (2 + j) * 2048 + col0);
      b1v[j][1] = *(const bf16x8*)(sb + bBase + (2 + j) * 2048 + col1);
    }
    __builtin_amdgcn_s_setprio(1);
    mfmaq<0, 0>(acc, aF, b0v);
    __builtin_amdgcn_s_setprio(0);
    BAR();

    // P2: stage A[t+2] chunks 0,2; lgkm0 (b1 drained); issue aHi(8); Q01
    if (st) { stageA(cur, t2, 0); stageA(cur, t2, 2); }
    BAR(); LGKM0();
#pragma unroll
    for (int i = 0; i < 4; ++i) {
      aH[i][0] = *(const bf16x8*)(sa + aBase + (4 + i) * 2048 + col0);
      aH[i][1] = *(const bf16x8*)(sa + aBase + (4 + i) * 2048 + col1);
    }
    __builtin_amdgcn_s_setprio(1);
    mfmaq<0, 1>(acc, aF, b1v);
    __builtin_amdgcn_s_setprio(0);
    BAR();

    // P3: stage B[t+2] chunks 0,1; lgkm0 (aHi drained); Q10
    if (st) { stageB(cur, t2, 0); stageB(cur, t2, 1); }
    BAR(); LGKM0();
    __builtin_amdgcn_s_setprio(1);
    mfmaq<1, 0>(acc, aH, b0v);
    __builtin_amdgcn_s_setprio(0);
    BAR();

    // P4: stage B2,B3,A1,A3; counted vmcnt validates buf^1; read b0(t+1)
    //     AND aLo(t+1) into Q11's shadow (drain across 2 barriers into P1)
    if (st) { stageB(cur, t2, 2); stageB(cur, t2, 3);
              stageA(cur, t2, 1); stageA(cur, t2, 3); }
    if (st) asm volatile("s_waitcnt vmcnt(8)" ::: "memory");
    else    asm volatile("s_waitcnt vmcnt(0)" ::: "memory");
    SCHEDB();                       // pin: buf^1 reads issue AFTER the vmcnt
    if (more) {
#pragma unroll
      for (int j = 0; j < 2; ++j) {
        b0v[j][0] = *(const bf16x8*)(sbN + bBase + j * 2048 + col0);
        b0v[j][1] = *(const bf16x8*)(sbN + bBase + j * 2048 + col1);
      }
#pragma unroll
      for (int i = 0; i < 4; ++i) {
        aF[i][0] = *(const bf16x8*)(saN + aBase + i * 2048 + col0);
        aF[i][1] = *(const bf16x8*)(saN + aBase + i * 2048 + col1);
      }
    }
    __builtin_amdgcn_s_setprio(1);
    mfmaq<1, 1>(acc, aH, b1v);
    __builtin_amdgcn_s_setprio(0);
    BAR();
  }

  if constexpr (EPI == 0) {
    int r0 = m0 + wm * 128 + kq * 4;
    int c0 = n0 + wn * 64 + lrow;
#pragma unroll
    for (int mi = 0; mi < 8; ++mi) {
#pragma unroll
      for (int q = 0; q < 4; ++q) {
        OutT* p = C + (size_t)(r0 + mi * 16 + q) * OSTR + c0;
#pragma unroll
        for (int ni = 0; ni < 4; ++ni) p[ni * 16] = (OutT)acc[mi][ni][q];
      }
    }
  } else {
    // Parallel silu fusion (r4 verified): gate wave (wn<2) pairs with up wave
    // (wn+2); rows split mi0-3 / mi4-7; 2-way max conflict exchange.
    float* xch = (float*)lds;
    bool isGate = (wn < 2);
    int p = wm * 2 + (wn & 1);
    float* mybuf = xch + (size_t)p * 8192 + (isGate ? 4096 : 0);
#pragma unroll
    for (int mi = 0; mi < 4; ++mi) {
      int msrc = isGate ? (4 + mi) : mi;
#pragma unroll
      for (int q = 0; q < 4; ++q) {
        int r = mi * 16 + kq * 4 + q;
        int key = (r >> 2) & 3;
#pragma unroll
        for (int ni = 0; ni < 4; ++ni) {
          int c = (ni * 16 + lrow) ^ (key << 4);
          mybuf[r * 64 + c] = acc[msrc][ni][q];
        }
      }
    }
    __syncthreads();
    const float* pbuf = xch + (size_t)p * 8192 + (isGate ? 0 : 4096);
    int mbase = isGate ? 0 : 4;
    int rowoff = isGate ? 0 : 64;
#pragma unroll
    for (int mi = 0; mi < 4; ++mi) {
#pragma unroll
      for (int q = 0; q < 4; ++q) {
        int r = mi * 16 + kq * 4 + q;
        int key = (r >> 2) & 3;
        int row = m0 + wm * 128 + rowoff + r;
        OutT* orow = C + (size_t)row * OSTR + tn * 128 + (wn & 1) * 64 + lrow;
#pragma unroll
        for (int ni = 0; ni < 4; ++ni) {
          int c = (ni * 16 + lrow) ^ (key << 4);
          float o = pbuf[r * 64 + c];
          float g = isGate ? acc[mbase + mi][ni][q] : o;
          float u = isGate ? o : acc[mbase + mi][ni][q];
          orow[ni * 16] = (OutT)(g / (1.f + __expf(-g)) * u);
        }
      }
    }
  }
}

// ---------------------------------------------------------------------------
extern "C" void kernel_launch(void* const* d_in, const int* in_sizes, int n_in,
                              void* d_out, int out_size, void* d_ws, size_t ws_size,
                              hipStream_t stream) {
  const float* x    = (const float*)d_in[0];
  const void*  mask = d_in[1];
  const float* Wg   = (const float*)d_in[2];
  const float* Wu   = (const float*)d_in[3];
  const float* Wd   = (const float*)d_in[4];
  const float* vAg  = (const float*)d_in[5];
  const float* vBg  = (const float*)d_in[6];
  const float* vAu  = (const float*)d_in[7];
  const float* vBu  = (const float*)d_in[8];
  const float* vAd  = (const float*)d_in[9];
  const float* vBd  = (const float*)d_in[10];
  const float* rg   = (const float*)d_in[11];
  const float* tmAg = (const float*)d_in[12];
  const float* tmBg = (const float*)d_in[13];
  const float* ru   = (const float*)d_in[14];
  const float* tmAu = (const float*)d_in[15];
  const float* tmBu = (const float*)d_in[16];
  const float* rd   = (const float*)d_in[17];
  const float* tmAd = (const float*)d_in[18];
  const float* tmBd = (const float*)d_in[19];

  // workspace layout (bytes), total 403,046,400:
  //   Xaug 0 .. 34,603,008
  //   Wcat 34,603,008 .. 220,594,176   (22016 x 4224 bf16, interleaved g/u)
  //   X2   220,594,176 .. 311,820,288  (4096 x 11136 bf16)
  //   Wda  311,820,288 .. 403,046,400  (4096 x 11136 bf16)
  // transient stashes in d_out (dead until gemm2 overwrites it completely):
  //   W88b = d_out + 0        (721 KB, consumed by prep_x)
  //   W44b = d_out + 1 MiB    (969 KB, consumed by prep_x2)
  char* ws = (char*)d_ws;
  __bf16* Xaug = (__bf16*)(ws);
  __bf16* Wcat = (__bf16*)(ws + 34603008);
  __bf16* X2   = (__bf16*)(ws + 220594176);
  __bf16* Wda  = (__bf16*)(ws + 311820288);
  __bf16* W88b = (__bf16*)d_out;
  __bf16* W44b = (__bf16*)((char*)d_out + 1048576);

  prepAll<<<I_DIM + 132 + H_DIM, 256, 0, stream>>>(
      Wg, Wu, Wd, vBg, tmBg, vBu, tmBu, vBd, tmBd,
      vAg, tmAg, rg, vAu, tmAu, ru, vAd, tmAd, rd,
      Wcat, Wda, W88b, W44b);
  prep_x<<<N_TOK / 4, 256, 0, stream>>>(x, mask, W88b, Xaug);

  // GEMM1 fused: grid 16*86 = 1376; L3 supertile map; silu(g)*u into X2
  gemm256<K1P, K1P / 64, 86, __bf16, K2P, 1, 2>
      <<<(N_TOK / 256) * 86, 512, 0, stream>>>(Xaug, Wcat, X2);

  prep_x2<<<N_TOK / 2, 512, 0, stream>>>(mask, W44b, X2);

  // GEMM2: grid 16*16 = 256, rectangle XCD map
  gemm256<K2P, K2P / 64, H_DIM / 256, float, H_DIM, 0, 1>
      <<<(N_TOK / 256) * (H_DIM / 256), 512, 0, stream>>>(X2, Wda, (float*)d_out);
}